// Round 15
// baseline (116.891 us; speedup 1.0000x reference)
//
#include <hip/hip_runtime.h>
#include <hip/hip_bf16.h>
#include <math.h>

// ---- problem constants (fixed by setup_inputs) ----
constexpr int B   = 4;
constexpr int S   = 4096;
constexpr int D   = 64;
constexpr int NH  = 8;        // hash rounds
constexpr int NB  = 64;       // buckets per hash
constexpr int NBT = 512;      // total buckets = NH*NB
constexpr int NI  = NH * S;   // items per batch = 32768
constexpr int NCH = 512;      // chunks per batch (of 64)
constexpr int CHB = 256;      // sort chunks per batch (of 128)

typedef __attribute__((ext_vector_type(8))) _Float16 f16x8;
typedef __attribute__((ext_vector_type(2))) __fp16 fp16x2;
typedef __attribute__((ext_vector_type(4))) float f32x4;
typedef __attribute__((ext_vector_type(2))) unsigned short u16x2;

constexpr float LOG2E = 1.44269504088896341f;

__device__ __forceinline__ unsigned short f16b(float x) {
    _Float16 h = (_Float16)x;
    return __builtin_bit_cast(unsigned short, h);
}
// per-16-bit-half "not equal" indicator (0 if equal, 1 if not)
__device__ __forceinline__ u16x2 nm2(int a, int b) {
    u16x2 x = __builtin_bit_cast(u16x2, a ^ b);
    u16x2 one = {1, 1};
    return __builtin_elementwise_min(x, one);
}
// packed f16 pair from two floats (RTZ)
__device__ __forceinline__ unsigned pk16(float a, float b) {
    fp16x2 hp = __builtin_amdgcn_cvt_pkrtz(a, b);
    return __builtin_bit_cast(unsigned, hp);
}
// DPP cross-lane; 0x121/2/4/8 = row_ror:N, 0xB1 = quad_perm[1,0,3,2]
template <int CTRL>
__device__ __forceinline__ float dppf(float x) {
    return __builtin_bit_cast(float,
        __builtin_amdgcn_update_dpp(__builtin_bit_cast(int, x), __builtin_bit_cast(int, x),
                                    CTRL, 0xF, 0xF, false));
}

// ============================================================
// K1: LSH hashing (register-tiled GEMM + argmax); hist -> counts[b][bkt][32]
//     + atomic tot accumulation (tot pre-zeroed by memset node)
//     + fused f16 prep: each block preps 16 token rows (uniform load)
// grid: B*NH*32 = 1024 blocks, 256 threads; block covers 128 tokens
// ============================================================
__global__ __launch_bounds__(256)
void k_hash(const float* __restrict__ q, const float* __restrict__ k,
            const float* __restrict__ v, const float* __restrict__ rot,
            int* __restrict__ buckets, int* __restrict__ counts, int* __restrict__ tot,
            unsigned short* __restrict__ q16, unsigned short* __restrict__ kn16,
            unsigned short* __restrict__ v16) {
    int blk = blockIdx.x;
    int tko = blk & 31, h = (blk >> 5) & 7, b = blk >> 8;
    __shared__ __align__(16) float rs[64 * 36];   // [d][n] padded
    __shared__ int hist[64];
    int tid = threadIdx.x;
    if (tid < 64) hist[tid] = 0;
    for (int i = tid; i < 2048; i += 256) {
        int nn = i & 31, d = i >> 5;
        rs[d * 36 + nn] = rot[(d * 8 + h) * 32 + nn];
    }
    __syncthreads();
    int ng = tid & 7, tg = tid >> 3;
    int t0 = tko * 128 + tg * 4;
    const float* qp = q + ((size_t)b * S + t0) * 64;
    float acc[4][4] = {};
    #pragma unroll 4
    for (int d4 = 0; d4 < 16; ++d4) {
        f32x4 r4[4];
        #pragma unroll
        for (int dd = 0; dd < 4; ++dd)
            r4[dd] = *(const f32x4*)(rs + (4 * d4 + dd) * 36 + 4 * ng);
        #pragma unroll
        for (int i = 0; i < 4; ++i) {
            f32x4 q4 = *(const f32x4*)(qp + i * 64 + d4 * 4);
            #pragma unroll
            for (int dd = 0; dd < 4; ++dd)
                #pragma unroll
                for (int c = 0; c < 4; ++c)
                    acc[i][c] += q4[dd] * r4[dd][c];
        }
    }
    #pragma unroll
    for (int i = 0; i < 4; ++i) {
        float vp = -3.402823466e38f, vn = -3.402823466e38f;
        int ip = 0, in_ = 0;
        #pragma unroll
        for (int c = 0; c < 4; ++c) {
            float a = acc[i][c]; int idx = 4 * ng + c;
            if (a > vp)  { vp = a;  ip = idx; }
            if (-a > vn) { vn = -a; in_ = idx; }
        }
        #pragma unroll
        for (int off = 1; off < 8; off <<= 1) {
            float ov = __shfl_xor(vp, off); int oi = __shfl_xor(ip, off);
            if (ov > vp || (ov == vp && oi < ip)) { vp = ov; ip = oi; }
            ov = __shfl_xor(vn, off); oi = __shfl_xor(in_, off);
            if (ov > vn || (ov == vn && oi < in_)) { vn = ov; in_ = oi; }
        }
        if (ng == 0) {
            int bi = (vn > vp) ? (in_ + 32) : ip;   // tie -> positive half
            buckets[b * NI + h * 4096 + t0 + i] = bi + h * NB;
            atomicAdd(&hist[bi], 1);
        }
    }
    __syncthreads();
    if (tid < 64) {
        int cnt = hist[tid];
        counts[((size_t)b * NBT + h * 64 + tid) * 32 + tko] = cnt;
        atomicAdd(&tot[b * NBT + h * 64 + tid], cnt);
    }

    // ---- fused prep: 16 rows/block, 4 rows per pass (64 lanes/row) ----
    int lane = tid & 63;
    #pragma unroll
    for (int it = 0; it < 4; ++it) {
        int row = blk * 16 + it * 4 + (tid >> 6);
        size_t idx = (size_t)row * 64 + lane;
        float kv = k[idx];
        float ss = kv * kv;
        #pragma unroll
        for (int m = 1; m < 64; m <<= 1) ss += __shfl_xor(ss, m, 64);
        kn16[idx] = f16b(kv * rsqrtf(ss));
        q16[idx]  = f16b(q[idx] * (0.125f * LOG2E));
        v16[idx]  = f16b(v[idx]);
    }
}

// ============================================================
// K4: stable scatter — cross-bucket scan (tot) + per-bucket chunk
//     prefix (counts[b][bkt][32]) + rank; writes spos, undo, locU
// grid: B*CHB = 1024 blocks, 128 threads
// ============================================================
__global__ void k_scatter(const int* __restrict__ buckets, const int* __restrict__ counts,
                          const int* __restrict__ tot, int* __restrict__ spos,
                          int* __restrict__ undo, unsigned short* __restrict__ locU) {
    int b = blockIdx.x >> 8, c = blockIdx.x & 255;
    int h = c >> 5, tko = c & 31;
    __shared__ __align__(16) int bk_s[128];
    __shared__ int sbase[NBT];
    __shared__ int pfx[64];
    __shared__ int wsum[2];
    int tid = threadIdx.x;
    int lane = tid & 63, w = tid >> 6;
    // ---- cross-bucket exclusive scan of tot[b][0..511] ----
    int4 tv = *(const int4*)(tot + b * NBT + tid * 4);
    int part = tv.x + tv.y + tv.z + tv.w;
    int incl = part;
    #pragma unroll
    for (int off = 1; off < 64; off <<= 1) {
        int t_ = __shfl_up(incl, off);
        if (lane >= off) incl += t_;
    }
    if (lane == 63) wsum[w] = incl;
    // ---- per-bucket chunk prefix (chunks < tko), 2 threads/bucket ----
    int bl = tid >> 1, hf = tid & 1;
    const int* crow = counts + ((size_t)b * NBT + h * 64 + bl) * 32 + hf * 16;
    int ps = 0;
    #pragma unroll
    for (int jj = 0; jj < 4; ++jj) {
        int4 cv = *(const int4*)(crow + jj * 4);
        int bi = hf * 16 + jj * 4;
        ps += (bi + 0 < tko) ? cv.x : 0;
        ps += (bi + 1 < tko) ? cv.y : 0;
        ps += (bi + 2 < tko) ? cv.z : 0;
        ps += (bi + 3 < tko) ? cv.w : 0;
    }
    ps += __shfl_xor(ps, 1);
    int i_flat = c * 128 + tid;
    int bkt = buckets[b * NI + i_flat];
    bk_s[tid] = bkt;
    if (hf == 0) pfx[bl] = ps;
    __syncthreads();
    if (w == 1) incl += wsum[0];
    int excl = incl - part;
    sbase[4 * tid]     = excl;
    sbase[4 * tid + 1] = excl + tv.x;
    sbase[4 * tid + 2] = excl + tv.x + tv.y;
    sbase[4 * tid + 3] = excl + tv.x + tv.y + tv.z;
    __syncthreads();
    // ---- stable rank via int4 LDS reads (broadcast, conflict-free) ----
    int rank = 0;
    #pragma unroll 8
    for (int j4 = 0; j4 < 32; ++j4) {
        int4 vv = *(const int4*)(bk_s + 4 * j4);
        int j = 4 * j4;
        rank += (j + 0 < tid && vv.x == bkt);
        rank += (j + 1 < tid && vv.y == bkt);
        rank += (j + 2 < tid && vv.z == bkt);
        rank += (j + 3 < tid && vv.w == bkt);
    }
    int pos = sbase[bkt] + pfx[bkt - h * 64] + rank;
    spos[b * NI + pos] = (i_flat & 4095) | (bkt << 12);   // t | bkt<<12
    undo[b * NI + i_flat] = pos;
    int t = i_flat & 4095;
    locU[(((size_t)b << 12) | t) * 8 + h] =
        (unsigned short)(((bkt & 63) << 9) | (pos >> 6));
}

__device__ __forceinline__ int bump_loc(int k1) {
    return (k1 & 0x7E007E00) | ((k1 + 0x00010001) & 0x01FF01FF);
}

// ============================================================
// K6: chunked attention via f16 MFMA — TWO chunks per block.
//   512 threads = 2 independent 256-thread groups, each with its
//   own 31 KB LDS slice (identical code => barriers align).
//   Tests block-granular residency: 8 waves/block instead of 4.
// grid: B*NCH/2 = 1024 blocks
// ============================================================
__global__ __launch_bounds__(512, 2)
void k_attn(const unsigned short* __restrict__ q16, const unsigned short* __restrict__ kn16,
            const unsigned short* __restrict__ v16, const int* __restrict__ spos,
            const int4* __restrict__ loc1P, unsigned short* __restrict__ soh,
            float* __restrict__ slog) {
    __shared__ __align__(16) char buf2[63488];
    int tidf = threadIdx.x;
    int g = tidf >> 8;                 // chunk group 0/1
    int tid = tidf & 255;
    int n = ((blockIdx.x & 255) << 1) | g;
    int b = blockIdx.x >> 8;
    char* buf = buf2 + g * 31744;
    unsigned short* ks = (unsigned short*)buf;            // [128][72] f16
    unsigned short* vh = (unsigned short*)buf;            // [64][136] v^T (overlays ks)
    unsigned short* ph = (unsigned short*)(buf + 18432);  // [64][72] wave-private
    int* klocs1 = (int*)(buf + 27648);                    // [128][4]
    int* qlocs  = (int*)(buf + 29696);                    // [64][4]
    int* mq     = (int*)(buf + 30720);                    // [64]  t|bkt<<12
    int* mk     = (int*)(buf + 30976);                    // [128]

    int bni = b * NI;
    const unsigned short* q16b = q16 + ((size_t)b << 12) * 64;
    const unsigned short* kn16b = kn16 + ((size_t)b << 12) * 64;
    const unsigned short* v16b = v16 + ((size_t)b << 12) * 64;

    // ---- phase A: sorted-position metadata ----
    if (tid < 64) mq[tid] = spos[bni + n * 64 + tid];
    else if (tid < 192) {
        int z = tid - 64;
        int nn = (z < 64) ? n : ((n + 511) & 511);   // z>=64: previous chunk
        mk[z] = spos[bni + nn * 64 + (z & 63)];
    }
    __syncthreads();

    int li = tid & 15, hi4 = (tid >> 4) & 3, w = tid >> 6;

    // ---- phase B: stage k tile + loc tables; Q A-frags from global ----
    #pragma unroll
    for (int it = 0; it < 4; ++it) {                  // k: 1024 16B-chunks
        int i = it * 256 + tid;
        int row = i >> 3, c8 = i & 7;
        int t = mk[row] & 4095;
        uint4 val = *(const uint4*)(kn16b + (size_t)t * 64 + c8 * 8);
        *(uint4*)(ks + row * 72 + c8 * 8) = val;
    }
    if (tid < 128) {
        int t = mk[tid] & 4095;
        *(int4*)(klocs1 + tid * 4) = loc1P[((size_t)b << 12) | t];
    } else if (tid < 192) {
        int r = tid - 128;
        int tq = mq[r] & 4095;
        *(int4*)(qlocs + r * 4) = loc1P[((size_t)b << 12) | tq];
    }
    int myqrow = mq[16 * w + li] & 4095;              // own A-row (wave-local)
    f16x8 a0 = *(const f16x8*)(q16b + (size_t)myqrow * 64 + 8 * hi4);
    f16x8 a1 = *(const f16x8*)(q16b + (size_t)myqrow * 64 + 32 + 8 * hi4);
    __syncthreads();

    // ---- phase C: QK^T via MFMA (scores in log2 domain) ----
    f32x4 sacc[8];
    #pragma unroll
    for (int zt = 0; zt < 8; ++zt) {
        f16x8 b0 = *(f16x8*)(ks + (16 * zt + li) * 72 + 8 * hi4);
        f16x8 b1 = *(f16x8*)(ks + (16 * zt + li) * 72 + 32 + 8 * hi4);
        f32x4 c = {0.f, 0.f, 0.f, 0.f};
        c = __builtin_amdgcn_mfma_f32_16x16x32_f16(a0, b0, c, 0, 0, 0);
        c = __builtin_amdgcn_mfma_f32_16x16x32_f16(a1, b1, c, 0, 0, 0);
        sacc[zt] = c;
    }

    // ---- phase D: masks + packed dup correction + softmax (log2 domain) ----
    int tqr[4], bqr[4];
    int4 lq[4];
    #pragma unroll
    for (int j = 0; j < 4; ++j) {
        int R = 16 * w + 4 * hi4 + j;
        int m = mq[R];
        tqr[j] = m & 4095; bqr[j] = m >> 12;
        lq[j] = *(const int4*)(qlocs + R * 4);
    }
    #pragma unroll
    for (int zt = 0; zt < 8; ++zt) {
        int z = 16 * zt + li;
        int mz = mk[z]; int tk = mz & 4095, bk = mz >> 12;
        int4 k1 = *(const int4*)(klocs1 + z * 4);
        int4 k2;
        k2.x = bump_loc(k1.x); k2.y = bump_loc(k1.y);
        k2.z = bump_loc(k1.z); k2.w = bump_loc(k1.w);
        #pragma unroll
        for (int j = 0; j < 4; ++j) {
            float s = sacc[zt][j];
            if (tqr[j] == tk) s = -14426.950408f;     // -10000 * log2(e)
            if (bqr[j] != bk) s = -3.402823466e38f;
            u16x2 acc = nm2(lq[j].x, k1.x);
            acc = acc + nm2(lq[j].y, k1.y);
            acc = acc + nm2(lq[j].z, k1.z);
            acc = acc + nm2(lq[j].w, k1.w);
            acc = acc + nm2(lq[j].x, k2.x);
            acc = acc + nm2(lq[j].y, k2.y);
            acc = acc + nm2(lq[j].z, k2.z);
            acc = acc + nm2(lq[j].w, k2.w);
            unsigned ua = __builtin_bit_cast(unsigned, acc);
            int dup = 16 - (int)((ua & 0xffffu) + (ua >> 16));
            s -= log2f(fmaxf((float)dup, 1.0f));
            sacc[zt][j] = s;
        }
    }

    float inv[4];
    #pragma unroll
    for (int j = 0; j < 4; ++j) {
        float m = sacc[0][j];
        #pragma unroll
        for (int zt = 1; zt < 8; ++zt) m = fmaxf(m, sacc[zt][j]);
        m = fmaxf(m, dppf<0x121>(m));    // row_ror:1
        m = fmaxf(m, dppf<0x122>(m));    // row_ror:2
        m = fmaxf(m, dppf<0x124>(m));    // row_ror:4
        m = fmaxf(m, dppf<0x128>(m));    // row_ror:8
        float sum = 0.f;
        #pragma unroll
        for (int zt = 0; zt < 8; ++zt) {
            float e = exp2f(sacc[zt][j] - m);
            sacc[zt][j] = e; sum += e;
        }
        sum += dppf<0x121>(sum);
        sum += dppf<0x122>(sum);
        sum += dppf<0x124>(sum);
        sum += dppf<0x128>(sum);
        float lse = m + log2f(sum);      // log2-domain lse
        inv[j] = __builtin_amdgcn_rcpf(sum);
        if (li == 0) slog[bni + n * 64 + 16 * w + 4 * hi4 + j] = lse;
    }
    __syncthreads();   // all ks reads complete before vh overlays

    // ---- phase E: gather V global->LDS (transposed, conflict-free writes) ----
    #pragma unroll
    for (int it = 0; it < 8; ++it) {
        int i = it * 256 + tid;          // 0..2047
        int zp = i & 63;                 // z = 2zp, 2zp+1 (per-lane)
        int dp = i >> 6;                 // d = 2dp, 2dp+1 (per-wave const)
        int t0 = mk[2 * zp] & 4095, t1 = mk[2 * zp + 1] & 4095;
        unsigned a = *(const unsigned*)(v16b + (size_t)t0 * 64 + 2 * dp);
        unsigned c = *(const unsigned*)(v16b + (size_t)t1 * 64 + 2 * dp);
        *(unsigned*)(vh + (2 * dp) * 136 + 2 * zp)     = __builtin_amdgcn_perm(c, a, 0x05040100u);
        *(unsigned*)(vh + (2 * dp + 1) * 136 + 2 * zp) = __builtin_amdgcn_perm(c, a, 0x07060302u);
    }
    __syncthreads();   // vh ready

    // ---- phase F: per z-half, wave-private P write + PV (no barriers) ----
    f32x4 oacc[4] = {{0,0,0,0},{0,0,0,0},{0,0,0,0},{0,0,0,0}};
    #pragma unroll
    for (int half = 0; half < 2; ++half) {
        #pragma unroll
        for (int zt4 = 0; zt4 < 4; ++zt4) {
            int zt = half * 4 + zt4;
            #pragma unroll
            for (int j = 0; j < 4; ++j) {
                float p  = sacc[zt][j] * inv[j];
                float po = dppf<0xB1>(p);            // quad_perm [1,0,3,2]
                if ((li & 1) == 0) {
                    int R  = 16 * w + 4 * hi4 + j;   // own wave's rows
                    int zl = 16 * zt4 + li;          // even
                    *(unsigned*)(ph + R * 72 + zl) = pk16(p, po);
                }
            }
        }
        #pragma unroll
        for (int step = 0; step < 2; ++step) {
            f16x8 pa = *(f16x8*)(ph + (16 * w + li) * 72 + 32 * step + 8 * hi4);
            #pragma unroll
            for (int nt = 0; nt < 4; ++nt) {
                f16x8 vb = *(f16x8*)(vh + (16 * nt + li) * 136 + 64 * half + 32 * step + 8 * hi4);
                oacc[nt] = __builtin_amdgcn_mfma_f32_16x16x32_f16(pa, vb, oacc[nt], 0, 0, 0);
            }
        }
    }

    // ---- epilogue: pack O to f16 pairs ----
    size_t ob = ((size_t)bni + n * 64) * 64;
    #pragma unroll
    for (int nt = 0; nt < 4; ++nt)
        #pragma unroll
        for (int j = 0; j < 4; ++j) {
            float o  = oacc[nt][j];
            float oo = dppf<0xB1>(o);
            if ((li & 1) == 0) {
                *(unsigned*)(soh + ob + (size_t)(16 * w + 4 * hi4 + j) * 64 + 16 * nt + li) =
                    pk16(o, oo);
            }
        }
}

// ============================================================
// K7: unsort + combine across hash rounds (f16 so, log2-domain logits)
// ============================================================
__global__ void k_comb(const int* __restrict__ undo, const float* __restrict__ slog,
                       const unsigned short* __restrict__ soh, float* __restrict__ out) {
    int flatT = blockIdx.x * 4 + (threadIdx.x >> 6);
    int lane  = threadIdx.x & 63;
    int b = flatT >> 12, t = flatT & (S - 1);
    int ph[NH]; float lg[NH];
    float m = -3.402823466e38f;
#pragma unroll
    for (int h = 0; h < NH; ++h) {
        ph[h] = undo[b * NI + (h << 12) + t];
        lg[h] = slog[b * NI + ph[h]];
        m = fmaxf(m, lg[h]);
    }
    float sum = 0.f;
#pragma unroll
    for (int h = 0; h < NH; ++h) sum += exp2f(lg[h] - m);
    float lse2 = m + log2f(sum);
    float o = 0.f;
#pragma unroll
    for (int h = 0; h < NH; ++h) {
        float wgt = exp2f(lg[h] - lse2);
        _Float16 hv = *(const _Float16*)(soh + ((size_t)b * NI + ph[h]) * D + lane);
        o += wgt * (float)hv;
    }
    out[(size_t)flatT * D + lane] = o;
}

// ============================================================
extern "C" void kernel_launch(void* const* d_in, const int* in_sizes, int n_in,
                              void* d_out, int out_size, void* d_ws, size_t ws_size,
                              hipStream_t stream) {
    const float* q   = (const float*)d_in[0];
    const float* k   = (const float*)d_in[1];
    const float* v   = (const float*)d_in[2];
    const float* rot = (const float*)d_in[3];
    float* out = (float*)d_out;

    char* ws = (char*)d_ws;
    size_t off = 0;
    auto alloc = [&](size_t bytes) -> void* {
        void* p = ws + off;
        off += (bytes + 255) & ~(size_t)255;
        return p;
    };
    unsigned short* q16  = (unsigned short*)alloc((size_t)B * S * D * 2);
    unsigned short* kn16 = (unsigned short*)alloc((size_t)B * S * D * 2);
    unsigned short* v16  = (unsigned short*)alloc((size_t)B * S * D * 2);
    unsigned short* soh  = (unsigned short*)alloc((size_t)B * NI * D * 2);
    float* slog    = (float*)alloc((size_t)B * NI * 4);
    int*   buckets = (int*)alloc((size_t)B * NI * 4);
    int*   counts  = (int*)alloc((size_t)B * NBT * 32 * 4);
    int*   tot     = (int*)alloc((size_t)B * NBT * 4);
    int*   spos    = (int*)alloc((size_t)B * NI * 4);
    int*   undo    = (int*)alloc((size_t)B * NI * 4);
    unsigned short* locU = (unsigned short*)alloc((size_t)B * S * NH * 2);

    hipMemsetAsync(tot, 0, (size_t)B * NBT * 4, stream);
    k_hash<<<1024, 256, 0, stream>>>(q, k, v, rot, buckets, counts, tot, q16, kn16, v16);
    k_scatter<<<B * CHB, 128, 0, stream>>>(buckets, counts, tot, spos, undo, locU);
    k_attn<<<B * NCH / 2, 512, 0, stream>>>(q16, kn16, v16, spos, (const int4*)locU, soh, slog);
    k_comb<<<B * S / 4, 256, 0, stream>>>(undo, slog, soh, out);
}

// Round 16
// 88.787 us; speedup vs baseline: 1.3165x; 1.3165x over previous
//
#include <hip/hip_runtime.h>
#include <hip/hip_bf16.h>
#include <math.h>

// ---- problem constants (fixed by setup_inputs) ----
constexpr int B   = 4;
constexpr int S   = 4096;
constexpr int D   = 64;
constexpr int NH  = 8;        // hash rounds
constexpr int NB  = 64;       // buckets per hash
constexpr int NBT = 512;      // total buckets = NH*NB
constexpr int NI  = NH * S;   // items per batch = 32768
constexpr int NCH = 512;      // chunks per batch (of 64)
constexpr int CHB = 256;      // sort chunks per batch (of 128)

typedef __attribute__((ext_vector_type(8))) _Float16 f16x8;
typedef __attribute__((ext_vector_type(2))) __fp16 fp16x2;
typedef __attribute__((ext_vector_type(4))) float f32x4;
typedef __attribute__((ext_vector_type(2))) unsigned short u16x2;

constexpr float LOG2E = 1.44269504088896341f;

__device__ __forceinline__ unsigned short f16b(float x) {
    _Float16 h = (_Float16)x;
    return __builtin_bit_cast(unsigned short, h);
}
// per-16-bit-half "not equal" indicator (0 if equal, 1 if not)
__device__ __forceinline__ u16x2 nm2(int a, int b) {
    u16x2 x = __builtin_bit_cast(u16x2, a ^ b);
    u16x2 one = {1, 1};
    return __builtin_elementwise_min(x, one);
}
// packed f16 pair from two floats (RTZ)
__device__ __forceinline__ unsigned pk16(float a, float b) {
    fp16x2 hp = __builtin_amdgcn_cvt_pkrtz(a, b);
    return __builtin_bit_cast(unsigned, hp);
}
// DPP cross-lane; 0x121/2/4/8 = row_ror:N, 0xB1 = quad_perm[1,0,3,2]
template <int CTRL>
__device__ __forceinline__ float dppf(float x) {
    return __builtin_bit_cast(float,
        __builtin_amdgcn_update_dpp(__builtin_bit_cast(int, x), __builtin_bit_cast(int, x),
                                    CTRL, 0xF, 0xF, false));
}

// ============================================================
// K1: LSH hashing (register-tiled GEMM + argmax); hist -> counts[b][bkt][32]
//     + atomic tot accumulation (tot pre-zeroed by memset node)
//     + fused f16 prep: each block preps 16 token rows (uniform load)
// grid: B*NH*32 = 1024 blocks, 256 threads; block covers 128 tokens
// ============================================================
__global__ __launch_bounds__(256)
void k_hash(const float* __restrict__ q, const float* __restrict__ k,
            const float* __restrict__ v, const float* __restrict__ rot,
            int* __restrict__ buckets, int* __restrict__ counts, int* __restrict__ tot,
            unsigned short* __restrict__ q16, unsigned short* __restrict__ kn16,
            unsigned short* __restrict__ v16) {
    int blk = blockIdx.x;
    int tko = blk & 31, h = (blk >> 5) & 7, b = blk >> 8;
    __shared__ __align__(16) float rs[64 * 36];   // [d][n] padded
    __shared__ int hist[64];
    int tid = threadIdx.x;
    if (tid < 64) hist[tid] = 0;
    for (int i = tid; i < 2048; i += 256) {
        int nn = i & 31, d = i >> 5;
        rs[d * 36 + nn] = rot[(d * 8 + h) * 32 + nn];
    }
    __syncthreads();
    int ng = tid & 7, tg = tid >> 3;
    int t0 = tko * 128 + tg * 4;
    const float* qp = q + ((size_t)b * S + t0) * 64;
    float acc[4][4] = {};
    #pragma unroll 4
    for (int d4 = 0; d4 < 16; ++d4) {
        f32x4 r4[4];
        #pragma unroll
        for (int dd = 0; dd < 4; ++dd)
            r4[dd] = *(const f32x4*)(rs + (4 * d4 + dd) * 36 + 4 * ng);
        #pragma unroll
        for (int i = 0; i < 4; ++i) {
            f32x4 q4 = *(const f32x4*)(qp + i * 64 + d4 * 4);
            #pragma unroll
            for (int dd = 0; dd < 4; ++dd)
                #pragma unroll
                for (int c = 0; c < 4; ++c)
                    acc[i][c] += q4[dd] * r4[dd][c];
        }
    }
    #pragma unroll
    for (int i = 0; i < 4; ++i) {
        float vp = -3.402823466e38f, vn = -3.402823466e38f;
        int ip = 0, in_ = 0;
        #pragma unroll
        for (int c = 0; c < 4; ++c) {
            float a = acc[i][c]; int idx = 4 * ng + c;
            if (a > vp)  { vp = a;  ip = idx; }
            if (-a > vn) { vn = -a; in_ = idx; }
        }
        #pragma unroll
        for (int off = 1; off < 8; off <<= 1) {
            float ov = __shfl_xor(vp, off); int oi = __shfl_xor(ip, off);
            if (ov > vp || (ov == vp && oi < ip)) { vp = ov; ip = oi; }
            ov = __shfl_xor(vn, off); oi = __shfl_xor(in_, off);
            if (ov > vn || (ov == vn && oi < in_)) { vn = ov; in_ = oi; }
        }
        if (ng == 0) {
            int bi = (vn > vp) ? (in_ + 32) : ip;   // tie -> positive half
            buckets[b * NI + h * 4096 + t0 + i] = bi + h * NB;
            atomicAdd(&hist[bi], 1);
        }
    }
    __syncthreads();
    if (tid < 64) {
        int cnt = hist[tid];
        counts[((size_t)b * NBT + h * 64 + tid) * 32 + tko] = cnt;
        atomicAdd(&tot[b * NBT + h * 64 + tid], cnt);
    }

    // ---- fused prep: 16 rows/block, 4 rows per pass (64 lanes/row) ----
    int lane = tid & 63;
    #pragma unroll
    for (int it = 0; it < 4; ++it) {
        int row = blk * 16 + it * 4 + (tid >> 6);
        size_t idx = (size_t)row * 64 + lane;
        float kv = k[idx];
        float ss = kv * kv;
        #pragma unroll
        for (int m = 1; m < 64; m <<= 1) ss += __shfl_xor(ss, m, 64);
        kn16[idx] = f16b(kv * rsqrtf(ss));
        q16[idx]  = f16b(q[idx] * (0.125f * LOG2E));
        v16[idx]  = f16b(v[idx]);
    }
}

// ============================================================
// K4: stable scatter — cross-bucket scan (tot) + per-bucket chunk
//     prefix (counts[b][bkt][32]) + rank; writes spos, undo, locU
// grid: B*CHB = 1024 blocks, 128 threads
// ============================================================
__global__ void k_scatter(const int* __restrict__ buckets, const int* __restrict__ counts,
                          const int* __restrict__ tot, int* __restrict__ spos,
                          int* __restrict__ undo, unsigned short* __restrict__ locU) {
    int b = blockIdx.x >> 8, c = blockIdx.x & 255;
    int h = c >> 5, tko = c & 31;
    __shared__ __align__(16) int bk_s[128];
    __shared__ int sbase[NBT];
    __shared__ int pfx[64];
    __shared__ int wsum[2];
    int tid = threadIdx.x;
    int lane = tid & 63, w = tid >> 6;
    // ---- cross-bucket exclusive scan of tot[b][0..511] ----
    int4 tv = *(const int4*)(tot + b * NBT + tid * 4);
    int part = tv.x + tv.y + tv.z + tv.w;
    int incl = part;
    #pragma unroll
    for (int off = 1; off < 64; off <<= 1) {
        int t_ = __shfl_up(incl, off);
        if (lane >= off) incl += t_;
    }
    if (lane == 63) wsum[w] = incl;
    // ---- per-bucket chunk prefix (chunks < tko), 2 threads/bucket ----
    int bl = tid >> 1, hf = tid & 1;
    const int* crow = counts + ((size_t)b * NBT + h * 64 + bl) * 32 + hf * 16;
    int ps = 0;
    #pragma unroll
    for (int jj = 0; jj < 4; ++jj) {
        int4 cv = *(const int4*)(crow + jj * 4);
        int bi = hf * 16 + jj * 4;
        ps += (bi + 0 < tko) ? cv.x : 0;
        ps += (bi + 1 < tko) ? cv.y : 0;
        ps += (bi + 2 < tko) ? cv.z : 0;
        ps += (bi + 3 < tko) ? cv.w : 0;
    }
    ps += __shfl_xor(ps, 1);
    int i_flat = c * 128 + tid;
    int bkt = buckets[b * NI + i_flat];
    bk_s[tid] = bkt;
    if (hf == 0) pfx[bl] = ps;
    __syncthreads();
    if (w == 1) incl += wsum[0];
    int excl = incl - part;
    sbase[4 * tid]     = excl;
    sbase[4 * tid + 1] = excl + tv.x;
    sbase[4 * tid + 2] = excl + tv.x + tv.y;
    sbase[4 * tid + 3] = excl + tv.x + tv.y + tv.z;
    __syncthreads();
    // ---- stable rank via int4 LDS reads (broadcast, conflict-free) ----
    int rank = 0;
    #pragma unroll 8
    for (int j4 = 0; j4 < 32; ++j4) {
        int4 vv = *(const int4*)(bk_s + 4 * j4);
        int j = 4 * j4;
        rank += (j + 0 < tid && vv.x == bkt);
        rank += (j + 1 < tid && vv.y == bkt);
        rank += (j + 2 < tid && vv.z == bkt);
        rank += (j + 3 < tid && vv.w == bkt);
    }
    int pos = sbase[bkt] + pfx[bkt - h * 64] + rank;
    spos[b * NI + pos] = (i_flat & 4095) | (bkt << 12);   // t | bkt<<12
    undo[b * NI + i_flat] = pos;
    int t = i_flat & 4095;
    locU[(((size_t)b << 12) | t) * 8 + h] =
        (unsigned short)(((bkt & 63) << 9) | (pos >> 6));
}

__device__ __forceinline__ int bump_loc(int k1) {
    return (k1 & 0x7E007E00) | ((k1 + 0x00010001) & 0x01FF01FF);
}

// ============================================================
// K6: chunked attention via f16 MFMA (64 q rows x 128 keys, d=64)
//   Q in registers; ph wave-private; V gathered COALESCED (uint4,
//   8 lanes/row -> 16x fewer cache-line transactions) and written
//   transposed to vh via b16 stores with XOR swizzle
//   byte ^= ((d>>3)&7)<<4 (conflict-free; same XOR on reads).
//   4 barriers. LDS 31.5 KB. launch_bounds(256,3).
// ============================================================
__global__ __launch_bounds__(256, 3)
void k_attn(const unsigned short* __restrict__ q16, const unsigned short* __restrict__ kn16,
            const unsigned short* __restrict__ v16, const int* __restrict__ spos,
            const int4* __restrict__ loc1P, unsigned short* __restrict__ soh,
            float* __restrict__ slog) {
    int n = blockIdx.x & 511, b = blockIdx.x >> 9;
    __shared__ __align__(16) char buf[31488];
    unsigned short* ks = (unsigned short*)buf;            // [128][72] f16
    char* vhB = buf;                                      // v^T overlay [64 d][136 z] swizzled
    unsigned short* ph = (unsigned short*)(buf + 18432);  // [64][72] wave-private
    int* klocs1 = (int*)(buf + 27648);                    // [128][4]
    int* qlocs  = (int*)(buf + 29696);                    // [64][4]
    int* mq     = (int*)(buf + 30720);                    // [64]  t|bkt<<12
    int* mk     = (int*)(buf + 30976);                    // [128]

    int tid = threadIdx.x;
    int bni = b * NI;
    const unsigned short* q16b = q16 + ((size_t)b << 12) * 64;
    const unsigned short* kn16b = kn16 + ((size_t)b << 12) * 64;
    const unsigned short* v16b = v16 + ((size_t)b << 12) * 64;

    // ---- phase A: sorted-position metadata ----
    if (tid < 64) mq[tid] = spos[bni + n * 64 + tid];
    else if (tid < 192) {
        int z = tid - 64;
        int nn = (z < 64) ? n : ((n + 511) & 511);   // z>=64: previous chunk
        mk[z] = spos[bni + nn * 64 + (z & 63)];
    }
    __syncthreads();

    int li = tid & 15, hi4 = (tid >> 4) & 3, w = tid >> 6;

    // ---- phase B: stage k tile + loc tables; Q A-frags from global ----
    #pragma unroll
    for (int it = 0; it < 4; ++it) {                  // k: 1024 16B-chunks
        int i = it * 256 + tid;
        int row = i >> 3, c8 = i & 7;
        int t = mk[row] & 4095;
        uint4 val = *(const uint4*)(kn16b + (size_t)t * 64 + c8 * 8);
        *(uint4*)(ks + row * 72 + c8 * 8) = val;
    }
    if (tid < 128) {
        int t = mk[tid] & 4095;
        *(int4*)(klocs1 + tid * 4) = loc1P[((size_t)b << 12) | t];
    } else if (tid < 192) {
        int r = tid - 128;
        int tq = mq[r] & 4095;
        *(int4*)(qlocs + r * 4) = loc1P[((size_t)b << 12) | tq];
    }
    int myqrow = mq[16 * w + li] & 4095;              // own A-row (wave-local)
    f16x8 a0 = *(const f16x8*)(q16b + (size_t)myqrow * 64 + 8 * hi4);
    f16x8 a1 = *(const f16x8*)(q16b + (size_t)myqrow * 64 + 32 + 8 * hi4);
    __syncthreads();

    // ---- phase C: QK^T via MFMA (scores in log2 domain) ----
    f32x4 sacc[8];
    #pragma unroll
    for (int zt = 0; zt < 8; ++zt) {
        f16x8 b0 = *(f16x8*)(ks + (16 * zt + li) * 72 + 8 * hi4);
        f16x8 b1 = *(f16x8*)(ks + (16 * zt + li) * 72 + 32 + 8 * hi4);
        f32x4 c = {0.f, 0.f, 0.f, 0.f};
        c = __builtin_amdgcn_mfma_f32_16x16x32_f16(a0, b0, c, 0, 0, 0);
        c = __builtin_amdgcn_mfma_f32_16x16x32_f16(a1, b1, c, 0, 0, 0);
        sacc[zt] = c;
    }

    // ---- phase D: masks + packed dup correction + softmax (log2 domain) ----
    int tqr[4], bqr[4];
    int4 lq[4];
    #pragma unroll
    for (int j = 0; j < 4; ++j) {
        int R = 16 * w + 4 * hi4 + j;
        int m = mq[R];
        tqr[j] = m & 4095; bqr[j] = m >> 12;
        lq[j] = *(const int4*)(qlocs + R * 4);
    }
    #pragma unroll
    for (int zt = 0; zt < 8; ++zt) {
        int z = 16 * zt + li;
        int mz = mk[z]; int tk = mz & 4095, bk = mz >> 12;
        int4 k1 = *(const int4*)(klocs1 + z * 4);
        int4 k2;
        k2.x = bump_loc(k1.x); k2.y = bump_loc(k1.y);
        k2.z = bump_loc(k1.z); k2.w = bump_loc(k1.w);
        #pragma unroll
        for (int j = 0; j < 4; ++j) {
            float s = sacc[zt][j];
            if (tqr[j] == tk) s = -14426.950408f;     // -10000 * log2(e)
            if (bqr[j] != bk) s = -3.402823466e38f;
            u16x2 acc = nm2(lq[j].x, k1.x);
            acc = acc + nm2(lq[j].y, k1.y);
            acc = acc + nm2(lq[j].z, k1.z);
            acc = acc + nm2(lq[j].w, k1.w);
            acc = acc + nm2(lq[j].x, k2.x);
            acc = acc + nm2(lq[j].y, k2.y);
            acc = acc + nm2(lq[j].z, k2.z);
            acc = acc + nm2(lq[j].w, k2.w);
            unsigned ua = __builtin_bit_cast(unsigned, acc);
            int dup = 16 - (int)((ua & 0xffffu) + (ua >> 16));
            s -= log2f(fmaxf((float)dup, 1.0f));
            sacc[zt][j] = s;
        }
    }

    float inv[4];
    #pragma unroll
    for (int j = 0; j < 4; ++j) {
        float m = sacc[0][j];
        #pragma unroll
        for (int zt = 1; zt < 8; ++zt) m = fmaxf(m, sacc[zt][j]);
        m = fmaxf(m, dppf<0x121>(m));    // row_ror:1
        m = fmaxf(m, dppf<0x122>(m));    // row_ror:2
        m = fmaxf(m, dppf<0x124>(m));    // row_ror:4
        m = fmaxf(m, dppf<0x128>(m));    // row_ror:8
        float sum = 0.f;
        #pragma unroll
        for (int zt = 0; zt < 8; ++zt) {
            float e = exp2f(sacc[zt][j] - m);
            sacc[zt][j] = e; sum += e;
        }
        sum += dppf<0x121>(sum);
        sum += dppf<0x122>(sum);
        sum += dppf<0x124>(sum);
        sum += dppf<0x128>(sum);
        float lse = m + log2f(sum);      // log2-domain lse
        inv[j] = __builtin_amdgcn_rcpf(sum);
        if (li == 0) slog[bni + n * 64 + 16 * w + 4 * hi4 + j] = lse;
    }
    __syncthreads();   // all ks reads complete before vh overlays

    // ---- phase E: COALESCED V gather (uint4, 8 lanes/row) + swizzled
    //      transpose-write to vh. byte ^= ((d>>3)&7)<<4 = c8<<4. ----
    #pragma unroll
    for (int it = 0; it < 4; ++it) {
        int i = it * 256 + tid;          // 0..1023
        int zr = i >> 3;                 // V row (z), 8 lanes each
        int c8 = i & 7;                  // 16B chunk -> d = 8*c8 .. 8*c8+7
        int t = mk[zr] & 4095;
        uint4 u = *(const uint4*)(v16b + (size_t)t * 64 + c8 * 8);
        int dbase = 8 * c8;
        unsigned wd[4] = {u.x, u.y, u.z, u.w};
        #pragma unroll
        for (int e = 0; e < 8; ++e) {
            int d = dbase + e;
            int off = ((d * 272 + 2 * zr) ^ (c8 << 4));
            *(unsigned short*)(vhB + off) = (unsigned short)(wd[e >> 1] >> (16 * (e & 1)));
        }
    }
    __syncthreads();   // vh ready

    // ---- phase F: per z-half, wave-private P write + PV (no barriers) ----
    f32x4 oacc[4] = {{0,0,0,0},{0,0,0,0},{0,0,0,0},{0,0,0,0}};
    #pragma unroll
    for (int half = 0; half < 2; ++half) {
        #pragma unroll
        for (int zt4 = 0; zt4 < 4; ++zt4) {
            int zt = half * 4 + zt4;
            #pragma unroll
            for (int j = 0; j < 4; ++j) {
                float p  = sacc[zt][j] * inv[j];
                float po = dppf<0xB1>(p);            // quad_perm [1,0,3,2]
                if ((li & 1) == 0) {
                    int R  = 16 * w + 4 * hi4 + j;   // own wave's rows
                    int zl = 16 * zt4 + li;          // even
                    *(unsigned*)(ph + R * 72 + zl) = pk16(p, po);
                }
            }
        }
        #pragma unroll
        for (int step = 0; step < 2; ++step) {
            f16x8 pa = *(f16x8*)(ph + (16 * w + li) * 72 + 32 * step + 8 * hi4);
            #pragma unroll
            for (int nt = 0; nt < 4; ++nt) {
                int d = 16 * nt + li;
                int zb2 = (64 * half + 32 * step + 8 * hi4) * 2;
                int off = ((d * 272 + zb2) ^ (((d >> 3) & 7) << 4));
                f16x8 vb = *(const f16x8*)(vhB + off);
                oacc[nt] = __builtin_amdgcn_mfma_f32_16x16x32_f16(pa, vb, oacc[nt], 0, 0, 0);
            }
        }
    }

    // ---- epilogue: pack O to f16 pairs ----
    size_t ob = ((size_t)bni + n * 64) * 64;
    #pragma unroll
    for (int nt = 0; nt < 4; ++nt)
        #pragma unroll
        for (int j = 0; j < 4; ++j) {
            float o  = oacc[nt][j];
            float oo = dppf<0xB1>(o);
            if ((li & 1) == 0) {
                *(unsigned*)(soh + ob + (size_t)(16 * w + 4 * hi4 + j) * 64 + 16 * nt + li) =
                    pk16(o, oo);
            }
        }
}

// ============================================================
// K7: unsort + combine across hash rounds (f16 so, log2-domain logits)
// ============================================================
__global__ void k_comb(const int* __restrict__ undo, const float* __restrict__ slog,
                       const unsigned short* __restrict__ soh, float* __restrict__ out) {
    int flatT = blockIdx.x * 4 + (threadIdx.x >> 6);
    int lane  = threadIdx.x & 63;
    int b = flatT >> 12, t = flatT & (S - 1);
    int ph[NH]; float lg[NH];
    float m = -3.402823466e38f;
#pragma unroll
    for (int h = 0; h < NH; ++h) {
        ph[h] = undo[b * NI + (h << 12) + t];
        lg[h] = slog[b * NI + ph[h]];
        m = fmaxf(m, lg[h]);
    }
    float sum = 0.f;
#pragma unroll
    for (int h = 0; h < NH; ++h) sum += exp2f(lg[h] - m);
    float lse2 = m + log2f(sum);
    float o = 0.f;
#pragma unroll
    for (int h = 0; h < NH; ++h) {
        float wgt = exp2f(lg[h] - lse2);
        _Float16 hv = *(const _Float16*)(soh + ((size_t)b * NI + ph[h]) * D + lane);
        o += wgt * (float)hv;
    }
    out[(size_t)flatT * D + lane] = o;
}

// ============================================================
extern "C" void kernel_launch(void* const* d_in, const int* in_sizes, int n_in,
                              void* d_out, int out_size, void* d_ws, size_t ws_size,
                              hipStream_t stream) {
    const float* q   = (const float*)d_in[0];
    const float* k   = (const float*)d_in[1];
    const float* v   = (const float*)d_in[2];
    const float* rot = (const float*)d_in[3];
    float* out = (float*)d_out;

    char* ws = (char*)d_ws;
    size_t off = 0;
    auto alloc = [&](size_t bytes) -> void* {
        void* p = ws + off;
        off += (bytes + 255) & ~(size_t)255;
        return p;
    };
    unsigned short* q16  = (unsigned short*)alloc((size_t)B * S * D * 2);
    unsigned short* kn16 = (unsigned short*)alloc((size_t)B * S * D * 2);
    unsigned short* v16  = (unsigned short*)alloc((size_t)B * S * D * 2);
    unsigned short* soh  = (unsigned short*)alloc((size_t)B * NI * D * 2);
    float* slog    = (float*)alloc((size_t)B * NI * 4);
    int*   buckets = (int*)alloc((size_t)B * NI * 4);
    int*   counts  = (int*)alloc((size_t)B * NBT * 32 * 4);
    int*   tot     = (int*)alloc((size_t)B * NBT * 4);
    int*   spos    = (int*)alloc((size_t)B * NI * 4);
    int*   undo    = (int*)alloc((size_t)B * NI * 4);
    unsigned short* locU = (unsigned short*)alloc((size_t)B * S * NH * 2);

    hipMemsetAsync(tot, 0, (size_t)B * NBT * 4, stream);
    k_hash<<<1024, 256, 0, stream>>>(q, k, v, rot, buckets, counts, tot, q16, kn16, v16);
    k_scatter<<<B * CHB, 128, 0, stream>>>(buckets, counts, tot, spos, undo, locU);
    k_attn<<<B * NCH, 256, 0, stream>>>(q16, kn16, v16, spos, (const int4*)locU, soh, slog);
    k_comb<<<B * S / 4, 256, 0, stream>>>(undo, slog, soh, out);
}